// Round 2
// baseline (460.688 us; speedup 1.0000x reference)
//
#include <hip/hip_runtime.h>

#define NZ    4000
#define NPAD  100
#define NZP   4100      // NZ + NPAD
#define NROW  8192      // 128 vels * 64 shots
#define NGRP  1025      // NZP / 4

// native clang vector types — required by __builtin_nontemporal_* (HIP's
// float4 is a class and is rejected by the builtin)
typedef float f32x4 __attribute__((ext_vector_type(4)));
typedef float f32x2 __attribute__((ext_vector_type(2)));

// Pure-streaming form: no LDS, no barrier. Halo comes from L1 (block row
// footprint 16.4 KB; halo float2 loads hit lines fetched by neighboring
// lanes' center float4 loads). Stores are nontemporal: 268 MB of
// write-once data must not evict the curr/prev/vel read streams from L2.
__global__ __launch_bounds__(256) void prop1d(
    const float* __restrict__ vel,     // [128, 4000] f32
    const float* __restrict__ wavelet, // [128] f32
    const int*   __restrict__ zs,      // [8192] int32, in [0,4000)
    const int*   __restrict__ zr,      // [8192] int32, in [0,4000)
    const float* __restrict__ prev,    // [8192, 4100] f32
    const float* __restrict__ curr,    // [8192, 4100] f32
    float* __restrict__ out0,          // curr passthrough (f32)
    float* __restrict__ out1,          // u_next (f32)
    float* __restrict__ out2,          // yt [8192] (f32)
    float* __restrict__ out3)          // regularizer [1] (f32)
{
    const int row = blockIdx.x;     // v*64 + s
    const int v   = row >> 6;
    const int tid = threadIdx.x;

    const float* __restrict__ crow = curr + (size_t)row * NZP;
    const float* __restrict__ prow = prev + (size_t)row * NZP;
    float* __restrict__ o0 = out0 + (size_t)row * NZP;
    float* __restrict__ o1 = out1 + (size_t)row * NZP;

    const int   zsr = zs[row];
    const int   zrr = zr[row];
    const float wf  = wavelet[v];

    // stencil taps: C4 = (dt/dz)^2 / 12 in double, rounded to f32 (matches np)
    const double C4d = (0.001 / 5.0) * (0.001 / 5.0) / 12.0;
    const float c0 = (float)(-C4d);
    const float c1 = (float)(16.0 * C4d);
    const float c2 = (float)(-30.0 * C4d);

    auto process = [&](int g) {
        const int zb = 4 * g;                 // first z of this group

        // center: curr[zb .. zb+3] (16B aligned: rows are 16400 B)
        const f32x4 cc = *(const f32x4*)(crow + zb);

        // halo: curr[zb-2], curr[zb-1], curr[zb+4], curr[zb+5]
        // (zero beyond [0, NZP) — matches jnp zero 'same' padding)
        float um2, um1, up4, up5;
        if (g != 0) {
            const f32x2 t = *(const f32x2*)(crow + zb - 2);   // 8B aligned
            um2 = t.x; um1 = t.y;
        } else {
            um2 = 0.0f; um1 = 0.0f;
        }
        if (g != NGRP - 1) {
            const f32x2 t = *(const f32x2*)(crow + zb + 4);   // 16B aligned
            up4 = t.x; up5 = t.y;
        } else {
            up4 = 0.0f; up5 = 0.0f;
        }

        // prev: read-once stream -> nontemporal
        const f32x4 pv = __builtin_nontemporal_load((const f32x4*)(prow + zb));

        float w0, w1, w2, w3;                 // vel^2 (edge-padded past NZ)
        if (g < 1000) {                       // zb+3 <= 3999
            const f32x4 vv = *(const f32x4*)(vel + v * NZ + zb);
            w0 = vv.x * vv.x; w1 = vv.y * vv.y; w2 = vv.z * vv.z; w3 = vv.w * vv.w;
        } else {                              // zb >= 4000 -> edge value
            const float a = vel[v * NZ + (NZ - 1)];
            w0 = w1 = w2 = w3 = a * a;
        }

        // identical FMA grouping to the verified kernel (bit-exact)
        const float l0 = c0 * (um2 + cc.z) + c1 * (um1 + cc.y) + c2 * cc.x;
        const float l1 = c0 * (um1 + cc.w) + c1 * (cc.x + cc.z) + c2 * cc.y;
        const float l2 = c0 * (cc.x + up4) + c1 * (cc.y + cc.w) + c2 * cc.z;
        const float l3 = c0 * (cc.y + up5) + c1 * (cc.z + up4) + c2 * cc.w;

        float n0 = l0 * w0 + 2.0f * cc.x - pv.x;
        float n1 = l1 * w1 + 2.0f * cc.y - pv.y;
        float n2 = l2 * w2 + 2.0f * cc.z - pv.z;
        float n3 = l3 * w3 + 2.0f * cc.w - pv.w;

        if (g < 1000) {
            // source injection (zs < 4000 where sponge mask == 1)
            const int d = zsr - zb;
            if ((unsigned)d < 4u) {
                if      (d == 0) n0 += wf;
                else if (d == 1) n1 += wf;
                else if (d == 2) n2 += wf;
                else             n3 += wf;
            }
        } else {
            // sponge: z >= 4000 -> exp(-(0.0015^2) * (z-3999)^2)
            const float k0 = (float)(zb - (NZ - 1));
            const float k1 = k0 + 1.0f, k2 = k0 + 2.0f, k3 = k0 + 3.0f;
            n0 *= expf(-2.25e-6f * k0 * k0);
            n1 *= expf(-2.25e-6f * k1 * k1);
            n2 *= expf(-2.25e-6f * k2 * k2);
            n3 *= expf(-2.25e-6f * k3 * k3);
        }

        // receiver readout (zr < 4000; mask==1 there)
        {
            const int d = zrr - zb;
            if ((unsigned)d < 4u) {
                out2[row] = (d == 0) ? n0 : (d == 1) ? n1 : (d == 2) ? n2 : n3;
            }
        }

        // streaming stores: out0 = curr passthrough (straight from load),
        // out1 = u_next; both write-once -> nontemporal
        __builtin_nontemporal_store(cc, (f32x4*)(o0 + zb));
        f32x4 ns; ns.x = n0; ns.y = n1; ns.z = n2; ns.w = n3;
        __builtin_nontemporal_store(ns, (f32x4*)(o1 + zb));
    };

    // groups 0..1023: fixed trip count 4 -> full unroll, all loads issue early
    #pragma unroll
    for (int k = 0; k < 4; ++k) process(tid + (k << 8));
    // tail group 1024 (z 4096..4099): one lane of the last wave
    if (tid == 255) process(1024);

    if (row == 0 && tid == 0) out3[0] = 0.0f;  // regularizer = 0
}

extern "C" void kernel_launch(void* const* d_in, const int* in_sizes, int n_in,
                              void* d_out, int out_size, void* d_ws, size_t ws_size,
                              hipStream_t stream) {
    const float* vel     = (const float*)d_in[0];
    const float* wavelet = (const float*)d_in[1];
    const int*   zs      = (const int*)d_in[2];
    const int*   zr      = (const int*)d_in[3];
    const float* prev    = (const float*)d_in[4];
    const float* curr    = (const float*)d_in[5];

    float* out0 = (float*)d_out;                       // [8192*4100]
    float* out1 = out0 + (size_t)NROW * NZP;           // [8192*4100]
    float* out2 = out1 + (size_t)NROW * NZP;           // [8192]
    float* out3 = out2 + NROW;                         // [1]

    prop1d<<<NROW, 256, 0, stream>>>(vel, wavelet, zs, zr, prev, curr,
                                     out0, out1, out2, out3);
}

// Round 3
// 456.848 us; speedup vs baseline: 1.0084x; 1.0084x over previous
//
#include <hip/hip_runtime.h>

#define NZ    4000
#define NPAD  100
#define NZP   4100      // NZ + NPAD
#define NROW  8192      // 128 vels * 64 shots
#define NGRP  1025      // NZP / 4

// native clang vector types — required by __builtin_nontemporal_*
typedef float f32x4 __attribute__((ext_vector_type(4)));
typedef float f32x2 __attribute__((ext_vector_type(2)));

// Hybrid form: the staging thread for group g IS the compute thread for
// group g, so the center float4 stays in registers across the barrier.
// LDS serves only the 4 halo floats per group (2x ds_read b64 instead of
// round-0's 8x ds_read_b32 with 8-way bank conflicts). No extra global
// halo loads (round-2's 2 extra vmem/group). prev load + both stores are
// nontemporal (write-once / read-once streams).
__global__ __launch_bounds__(256) void prop1d(
    const float* __restrict__ vel,     // [128, 4000] f32
    const float* __restrict__ wavelet, // [128] f32
    const int*   __restrict__ zs,      // [8192] int32, in [0,4000)
    const int*   __restrict__ zr,      // [8192] int32, in [0,4000)
    const float* __restrict__ prev,    // [8192, 4100] f32
    const float* __restrict__ curr,    // [8192, 4100] f32
    float* __restrict__ out0,          // curr passthrough (f32)
    float* __restrict__ out1,          // u_next (f32)
    float* __restrict__ out2,          // yt [8192] (f32)
    float* __restrict__ out3)          // regularizer [1] (f32)
{
    __shared__ float sc[NZP + 8];   // data at [4, 4+NZP), zero halo both sides
    const int row = blockIdx.x;     // v*64 + s
    const int v   = row >> 6;
    const int tid = threadIdx.x;

    const float* __restrict__ crow = curr + (size_t)row * NZP;
    const float* __restrict__ prow = prev + (size_t)row * NZP;
    float* __restrict__ o0 = out0 + (size_t)row * NZP;
    float* __restrict__ o1 = out1 + (size_t)row * NZP;

    if (tid < 8) sc[(tid < 4) ? tid : (NZP + tid)] = 0.0f;  // [0..3], [4104..4107]

    // stage curr into LDS, KEEPING each group's center float4 in registers
    f32x4 cc[4];
    #pragma unroll
    for (int k = 0; k < 4; ++k) {
        const int g = tid + (k << 8);                 // 0..1023
        cc[k] = *(const f32x4*)(crow + 4 * g);
        *(f32x4*)(&sc[4 + 4 * g]) = cc[k];
    }
    f32x4 cc4;                                        // tail group 1024
    if (tid == 0) {
        cc4 = *(const f32x4*)(crow + 4096);
        *(f32x4*)(&sc[4 + 4096]) = cc4;
    }
    __syncthreads();

    const int   zsr = zs[row];
    const int   zrr = zr[row];
    const float wf  = wavelet[v];

    // stencil taps: C4 = (dt/dz)^2 / 12 in double, rounded to f32 (matches np)
    const double C4d = (0.001 / 5.0) * (0.001 / 5.0) / 12.0;
    const float c0 = (float)(-C4d);
    const float c1 = (float)(16.0 * C4d);
    const float c2 = (float)(-30.0 * C4d);

    auto process = [&](int g, f32x4 c) {
        const int zb = 4 * g;                 // first z of this group

        // halo only from LDS: data indices zb-2, zb-1 -> sc[zb+2..3] (8B-aligned)
        //                     data indices zb+4, zb+5 -> sc[zb+8..9] (8B-aligned)
        const f32x2 lo = *(const f32x2*)(&sc[zb + 2]);
        const f32x2 hi = *(const f32x2*)(&sc[zb + 8]);
        const float um2 = lo.x, um1 = lo.y, up4 = hi.x, up5 = hi.y;

        // prev: read-once stream -> nontemporal
        const f32x4 pv = __builtin_nontemporal_load((const f32x4*)(prow + zb));

        float w0, w1, w2, w3;                 // vel^2 (edge-padded past NZ)
        if (g < 1000) {                       // zb+3 <= 3999
            const f32x4 vv = *(const f32x4*)(vel + v * NZ + zb);
            w0 = vv.x * vv.x; w1 = vv.y * vv.y; w2 = vv.z * vv.z; w3 = vv.w * vv.w;
        } else {                              // zb >= 4000 -> edge value
            const float a = vel[v * NZ + (NZ - 1)];
            w0 = w1 = w2 = w3 = a * a;
        }

        // identical FMA grouping to the verified kernel (bit-exact)
        const float l0 = c0 * (um2 + c.z) + c1 * (um1 + c.y) + c2 * c.x;
        const float l1 = c0 * (um1 + c.w) + c1 * (c.x + c.z) + c2 * c.y;
        const float l2 = c0 * (c.x + up4) + c1 * (c.y + c.w) + c2 * c.z;
        const float l3 = c0 * (c.y + up5) + c1 * (c.z + up4) + c2 * c.w;

        float n0 = l0 * w0 + 2.0f * c.x - pv.x;
        float n1 = l1 * w1 + 2.0f * c.y - pv.y;
        float n2 = l2 * w2 + 2.0f * c.z - pv.z;
        float n3 = l3 * w3 + 2.0f * c.w - pv.w;

        if (g < 1000) {
            // source injection (zs < 4000 where sponge mask == 1)
            const int d = zsr - zb;
            if ((unsigned)d < 4u) {
                if      (d == 0) n0 += wf;
                else if (d == 1) n1 += wf;
                else if (d == 2) n2 += wf;
                else             n3 += wf;
            }
        } else {
            // sponge: z >= 4000 -> exp(-(0.0015^2) * (z-3999)^2)
            const float k0 = (float)(zb - (NZ - 1));
            const float k1 = k0 + 1.0f, k2 = k0 + 2.0f, k3 = k0 + 3.0f;
            n0 *= expf(-2.25e-6f * k0 * k0);
            n1 *= expf(-2.25e-6f * k1 * k1);
            n2 *= expf(-2.25e-6f * k2 * k2);
            n3 *= expf(-2.25e-6f * k3 * k3);
        }

        // receiver readout (zr < 4000; mask==1 there; exactly one group matches)
        {
            const int d = zrr - zb;
            if ((unsigned)d < 4u) {
                out2[row] = (d == 0) ? n0 : (d == 1) ? n1 : (d == 2) ? n2 : n3;
            }
        }

        // streaming stores: out0 = curr passthrough (straight from register),
        // out1 = u_next; both write-once -> nontemporal
        __builtin_nontemporal_store(c, (f32x4*)(o0 + zb));
        f32x4 ns; ns.x = n0; ns.y = n1; ns.z = n2; ns.w = n3;
        __builtin_nontemporal_store(ns, (f32x4*)(o1 + zb));
    };

    #pragma unroll
    for (int k = 0; k < 4; ++k) process(tid + (k << 8), cc[k]);
    if (tid == 0) process(1024, cc4);     // tail group (z 4096..4099)

    if (row == 0 && tid == 0) out3[0] = 0.0f;  // regularizer = 0
}

extern "C" void kernel_launch(void* const* d_in, const int* in_sizes, int n_in,
                              void* d_out, int out_size, void* d_ws, size_t ws_size,
                              hipStream_t stream) {
    const float* vel     = (const float*)d_in[0];
    const float* wavelet = (const float*)d_in[1];
    const int*   zs      = (const int*)d_in[2];
    const int*   zr      = (const int*)d_in[3];
    const float* prev    = (const float*)d_in[4];
    const float* curr    = (const float*)d_in[5];

    float* out0 = (float*)d_out;                       // [8192*4100]
    float* out1 = out0 + (size_t)NROW * NZP;           // [8192*4100]
    float* out2 = out1 + (size_t)NROW * NZP;           // [8192]
    float* out3 = out2 + NROW;                         // [1]

    prop1d<<<NROW, 256, 0, stream>>>(vel, wavelet, zs, zr, prev, curr,
                                     out0, out1, out2, out3);
}